// Round 9
// baseline (279.394 us; speedup 1.0000x reference)
//
#include <hip/hip_runtime.h>
#include <hip/hip_cooperative_groups.h>
#include <math.h>

namespace cg = cooperative_groups;

#define BB 4
#define CC 64
#define HH_ 128
#define WW 128
#define HPW (HH_*WW)     // 16384
#define KH 64
#define KW 64
#define KSZ 7
#define AA 16
#define EPSV 1e-5f
#define KTOT 448         // 7*64
#define SMEM_BYTES 50688

typedef __attribute__((ext_vector_type(8))) short bf16x8;
typedef __attribute__((ext_vector_type(4))) float f32x4;
typedef unsigned short ushort_t;

__device__ __forceinline__ float sigm(float x){ return 1.0f/(1.0f+expf(-x)); }
__device__ __forceinline__ unsigned short f2bf(float f){
  unsigned u = __float_as_uint(f);
  return (unsigned short)((u + 0x7fffu + ((u>>16)&1u)) >> 16);
}

struct MegaArgs {
  const float *x, *weight, *ratio;
  const float *o1fc,*o1g,*o1b,*o1m,*o1v,*o1cw,*o1cb,*o1fw,*o1fb;
  const float *o2fc,*o2g,*o2b,*o2m,*o2v,*o2cw,*o2cb,*o2fw,*o2fb;
  const float *spw,*spb;
  const float *offw,*offb,*obg,*obb,*obm,*obv;
  const float *dsw,*dsb,*gng,*gnb;
  float *HHb, *weff, *partial, *gstat, *pstats, *outT;
  ushort_t *dsWbf, *offAbf, *outTbf;
  float *yout;
};

// ---------- P0: weight prep + DWT-HH + mean partials (grid 256, 2 chunks) ----------
__device__ __forceinline__ void phase0(const MegaArgs& a, int wg, int t, char* smem){
  int idx = wg*512 + t;
  if(idx < CC*KTOT){
    int co = idx/KTOT; int K = idx%KTOT; int k = K>>6; int ci = K&63;
    a.dsWbf[idx] = f2bf(a.dsw[(size_t)(co*CC+ci)*KSZ + k]);
  } else {
    int j2 = idx - CC*KTOT;
    if(j2 < 18*16*32){
      int kl = j2&31; int co = (j2>>5)&15; int s = j2>>9;
      int tap = s>>1; int ci = (s&1)*32 + kl;
      float v = 0.f;
      if(co<KSZ) v = a.offw[((size_t)co*CC + ci)*9 + tap];
      a.offAbf[j2] = f2bf(v);
    }
  }
  int lane = t&63, wid = t>>6;
  float* ls = (float*)smem;
  #pragma unroll
  for(int i=0;i<2;i++){
    int chunk = wg + i*256;            // 512 chunks of 2048 HH elements
    int e0 = chunk*2048 + t*4;
    int bc = e0>>12; int h2 = (e0>>6)&63; int w0 = e0&63;
    const float* xp = a.x + (size_t)bc*HPW;
    float4 a0 = *(const float4*)(xp + (2*h2)*WW + 2*w0);
    float4 a1 = *(const float4*)(xp + (2*h2)*WW + 2*w0 + 4);
    float4 b0 = *(const float4*)(xp + (2*h2+1)*WW + 2*w0);
    float4 b1 = *(const float4*)(xp + (2*h2+1)*WW + 2*w0 + 4);
    float4 hh;
    hh.x = 0.5f*(a0.x - b0.x - a0.y + b0.y);
    hh.y = 0.5f*(a0.z - b0.z - a0.w + b0.w);
    hh.z = 0.5f*(a1.x - b1.x - a1.y + b1.y);
    hh.w = 0.5f*(a1.z - b1.z - a1.w + b1.w);
    *(float4*)(a.HHb + e0) = hh;
    float s = a0.x+a0.y+a0.z+a0.w + a1.x+a1.y+a1.z+a1.w
            + b0.x+b0.y+b0.z+b0.w + b1.x+b1.y+b1.z+b1.w;
    for(int o=32;o>0;o>>=1) s += __shfl_down(s,o);
    if(lane==0) ls[wid] = s;
    __syncthreads();
    if(t==0){
      float tot=0.f;
      #pragma unroll
      for(int k2=0;k2<8;k2++) tot += ls[k2];
      a.partial[chunk] = tot;
    }
    __syncthreads();
  }
}

// ---------- P1: attention + weff (block = (b,o), lanes 0-63) ----------
__device__ __forceinline__ void phase1(const MegaArgs& a, int wg, int t){
  if(t < 64){
    int b = wg>>6, o = wg&63; int ci = t;
    int bc = b*CC+ci;
    float g_own = (a.partial[2*bc] + a.partial[2*bc+1]) * (1.0f/HPW);
    float d1=a.o1cb[ci], d2=a.o1fb[ci], d3=a.o2cb[ci], d4=a.o2fb[ci];
    float sspacc[9];
    #pragma unroll
    for(int e=0;e<9;e++) sspacc[e]=a.spb[e];
    for(int j=0;j<AA;j++){
      float p1 = g_own * a.o1fc[j*CC+ci];
      float p2 = g_own * a.o2fc[j*CC+ci];
      #pragma unroll
      for(int off=32;off>0;off>>=1){ p1+=__shfl_xor(p1,off); p2+=__shfl_xor(p2,off); }
      p1 = (p1-a.o1m[j])*rsqrtf(a.o1v[j]+EPSV)*a.o1g[j]+a.o1b[j]; p1=fmaxf(p1,0.f);
      p2 = (p2-a.o2m[j])*rsqrtf(a.o2v[j]+EPSV)*a.o2g[j]+a.o2b[j]; p2=fmaxf(p2,0.f);
      d1 += p1*a.o1cw[ci*AA+j]; d2 += p1*a.o1fw[ci*AA+j];
      d3 += p2*a.o2cw[ci*AA+j]; d4 += p2*a.o2fw[ci*AA+j];
      #pragma unroll
      for(int e=0;e<9;e++) sspacc[e] += p2*a.spw[e*AA+j];
    }
    float sc1v=sigm(d1), sc2v=sigm(d3);
    float sf1o=__shfl(sigm(d2),o), sf2o=__shfl(sigm(d4),o);
    const float* wp = a.weight + (size_t)(o*CC+ci)*9;
    float w9[9]; float m=0.f;
    #pragma unroll
    for(int e=0;e<9;e++){ w9[e]=wp[e]; m+=w9[e]; }
    m *= (1.0f/9.0f);
    float S1 = m * sc1v;
    float M[9];
    #pragma unroll
    for(int e=0;e<9;e++) M[e] = (w9[e]-m)*sc2v;
    #pragma unroll
    for(int off=32; off>0; off>>=1){
      S1 += __shfl_xor(S1, off);
      #pragma unroll
      for(int e=0;e<9;e++) M[e] += __shfl_xor(M[e], off);
    }
    if(ci==0){
      const float Dm[3][3] = {{2.f,2.f,2.f},{1.7320508075688772f,0.f,-1.7320508075688772f},{1.f,-2.f,1.f}};
      const float Di[3][3] = {{0.16666666666666666f,0.28867513459481287f,0.16666666666666666f},
                              {0.16666666666666666f,0.f,-0.3333333333333333f},
                              {0.16666666666666666f,-0.28867513459481287f,0.16666666666666666f}};
      float U[3][3], T[3][3], V[3][3], R[3][3];
      for(int k=0;k<3;k++)for(int n=0;n<3;n++) U[k][n]=Dm[k][0]*M[0*3+n]+Dm[k][1]*M[1*3+n]+Dm[k][2]*M[2*3+n];
      for(int k=0;k<3;k++)for(int l=0;l<3;l++) T[k][l]=(U[k][0]*Dm[l][0]+U[k][1]*Dm[l][1]+U[k][2]*Dm[l][2])*2.0f*sigm(sspacc[k*3+l]);
      for(int k=0;k<3;k++)for(int n=0;n<3;n++) V[k][n]=Di[k][0]*T[0][n]+Di[k][1]*T[1][n]+Di[k][2]*T[2][n];
      for(int k=0;k<3;k++)for(int l=0;l<3;l++) R[k][l]=V[k][0]*Di[l][0]+V[k][1]*Di[l][1]+V[k][2]*Di[l][2];
      float rr = a.ratio[0];
      float base = rr*4.0f*sf1o*S1;
      float w2f = (1.0f-rr)*4.0f*sf2o;
      #pragma unroll
      for(int e=0;e<9;e++) a.weff[(size_t)wg*9+e] = base + w2f*R[e/3][e%3];
    }
  }
}

// ---------- P2: iwt + transpose for one (b,h) tile ----------
__device__ __forceinline__ void phase2(const MegaArgs& a, int tile, int t, char* smem){
  int sw = (tile&7)*64 + (tile>>3);
  int b = sw>>7, h = sw&127;
  float* xt  = (float*)smem;            // [64][129]
  float* d_s = (float*)(smem + 33024);  // [64][65]
  int h2 = h>>1;
  int c = t>>3, q = t&7;
  float wk[9];
  #pragma unroll
  for(int e=0;e<9;e++) wk[e] = a.weff[(size_t)(b*CC+c)*9+e];
  const float* Hp = a.HHb + (size_t)(b*CC+c)*(KH*KW);
  #pragma unroll 2
  for(int j=0;j<8;j++){
    int w2 = q*8+j;
    float conv = 0.f;
    #pragma unroll
    for(int dh=-1;dh<=1;dh++){
      int r = h2+dh; if(r<0||r>=KH) continue;
      #pragma unroll
      for(int dw=-1;dw<=1;dw++){
        int wc2 = w2+dw; if(wc2<0||wc2>=KW) continue;
        conv += wk[(dh+1)*3+(dw+1)]*Hp[r*KW+wc2];
      }
    }
    d_s[c*65+w2] = 0.5f*(conv - Hp[h2*KW+w2]);
  }
  for(int e=t; e<CC*WW; e+=512){
    int cc=e>>7, w=e&127;
    xt[cc*129+w] = a.x[((size_t)(b*CC+cc)*HH_+h)*WW + w];
  }
  __syncthreads();
  float* dst = a.outT + ((size_t)(b*HH_+h))*WW*CC;
  ushort_t* dstb = a.outTbf + ((size_t)(b*HH_+h))*130*CC;
  for(int e=t; e<CC*WW; e+=512){
    int w=e>>6, cc=e&63;
    float dv = d_s[cc*65+(w>>1)];
    float val = 2.f*xt[cc*129+w] + (((h + w)&1) ? -dv : dv);
    dst[e] = val;
    dstb[(w+1)*CC + cc] = f2bf(val);
  }
  if(t<128){ int cc=t&63; int side=t>>6; dstb[(size_t)side*129*CC + cc] = 0; }
}

// ---------- P3: offset-conv + dy + deform-sample GEMM + GN partials for one tile ----------
__device__ __forceinline__ void phase3(const MegaArgs& a, int tile, int t, char* smem){
  int sw = (tile&7)*64 + (tile>>3);
  int b = sw>>7, h = sw&127;
  int lane = t&63, wid = t>>6;
  int arow = lane&15, kgrp = lane>>4;
  ushort_t* S2a = (ushort_t*)smem;                // 2 x 8192 shorts
  int*   sb0   = (int*)(smem + 32768);
  int*   sb1   = (int*)(smem + 36352);
  float* swr   = (float*)(smem + 39936);
  float* off_s = (float*)(smem + 43520);
  float* dy_s  = (float*)(smem + 47104);
  // Phase A: offset conv (8 waves, wave = one 16-wide w tile)
  {
    f32x4 acc = (f32x4){0.f,0.f,0.f,0.f};
    #pragma unroll
    for(int s=0;s<18;s++){
      int tap = s>>1, chalf = s&1;
      int r = tap/3, dwp = tap%3;
      int hr = h - 1 + r;
      if(hr<0 || hr>=HH_) continue;
      bf16x8 aF = *(const bf16x8*)(a.offAbf + (s*16+arow)*32 + kgrp*8);
      const ushort_t* base = a.outTbf + ((size_t)(b*HH_+hr))*130*CC + chalf*32 + kgrp*8;
      int wp = (wid<<4) + arow + dwp;
      bf16x8 bF = *(const bf16x8*)(base + (size_t)wp*CC);
      acc = __builtin_amdgcn_mfma_f32_16x16x32_bf16(aF, bF, acc, 0,0,0);
    }
    #pragma unroll
    for(int r=0;r<4;r++){
      int co = kgrp*4+r;
      if(co<KSZ) off_s[co*128 + (wid<<4) + arow] = acc[r];
    }
  }
  __syncthreads();
  // Phase B: BN + tanh + cumsum
  if(t<128){
    int w = t;
    float y[KSZ];
    #pragma unroll
    for(int k=0;k<KSZ;k++){
      float sc = a.obg[k]*rsqrtf(a.obv[k]+EPSV);
      float sh = a.obb[k]-a.obm[k]*sc;
      y[k] = tanhf((off_s[k*128+w]+a.offb[k])*sc+sh);
    }
    dy_s[      w]=y[0]+y[1]+y[2]; dy_s[128+w]=y[1]+y[2]; dy_s[256+w]=y[2];
    dy_s[384+w]=0.f; dy_s[512+w]=y[4]; dy_s[640+w]=y[4]+y[5]; dy_s[768+w]=y[4]+y[5]+y[6];
  }
  __syncthreads();
  // Phase C: sample meta
  for(int e=t; e<KSZ*128; e+=512){
    int k = e>>7, w = e&127;
    float dv = dy_s[e];
    float r = fminf(fmaxf((float)h + dv, 0.f), 127.f);
    float rf = floorf(r); int r0=(int)rf; float wr=r-rf; int r1=min(r0+1,127);
    int c = min(max(w+k-3,0),127);
    sb0[k*128+w] = ((b*HH_+r0)*WW+c)*CC;
    sb1[k*128+w] = ((b*HH_+r1)*WW+c)*CC;
    swr[k*128+w] = wr;
  }
  __syncthreads();
  // Phase D: K-chunked double-buffered sample + MFMA GEMM
  int cg2 = wid&3, wh = wid>>2;
  {
    ushort_t* buf = S2a;
    #pragma unroll
    for(int i=0;i<16;i++){
      int p = (wid<<4)+i;
      int b0=sb0[p], b1=sb1[p]; float wr=swr[p];
      float av = a.outT[b0+lane], c2 = a.outT[b1+lane];
      float v = av + wr*(c2-av);
      int idx = (p<<6)|lane;
      buf[idx ^ ((p&7)<<3)] = f2bf(v);
    }
  }
  __syncthreads();
  f32x4 acc[4];
  #pragma unroll
  for(int nt=0;nt<4;nt++) acc[nt] = (f32x4){0.f,0.f,0.f,0.f};
  int bufs = 0;
  for(int k=0;k<KSZ;k++){
    const ushort_t* Wp = a.dsWbf + (size_t)((cg2<<4)+arow)*KTOT + (k<<6) + kgrp*8;
    bf16x8 a0 = *(const bf16x8*)Wp;
    bf16x8 a1 = *(const bf16x8*)(Wp+32);
    if(k+1<KSZ){
      ushort_t* nb = S2a + (bufs^1)*8192;
      #pragma unroll
      for(int i=0;i<16;i++){
        int p = (wid<<4)+i;
        int b0=sb0[(k+1)*128+p], b1=sb1[(k+1)*128+p]; float wr=swr[(k+1)*128+p];
        float av = a.outT[b0+lane], c2 = a.outT[b1+lane];
        float v = av + wr*(c2-av);
        int idx = (p<<6)|lane;
        nb[idx ^ ((p&7)<<3)] = f2bf(v);
      }
    }
    const ushort_t* cb = S2a + bufs*8192;
    #pragma unroll
    for(int nt=0;nt<4;nt++){
      int pos = (wh<<6) + (nt<<4) + arow;
      int i0 = (pos<<6) + kgrp*8;
      int sz = (pos&7)<<3;
      bf16x8 b0 = *(const bf16x8*)(cb + (i0 ^ sz));
      bf16x8 b1 = *(const bf16x8*)(cb + ((i0+32) ^ sz));
      acc[nt] = __builtin_amdgcn_mfma_f32_16x16x32_bf16(a0, b0, acc[nt], 0,0,0);
      acc[nt] = __builtin_amdgcn_mfma_f32_16x16x32_bf16(a1, b1, acc[nt], 0,0,0);
    }
    __syncthreads();
    bufs ^= 1;
  }
  // epilogue
  float vs[4]={0.f,0.f,0.f,0.f}, vq[4]={0.f,0.f,0.f,0.f};
  #pragma unroll
  for(int r=0;r<4;r++){
    int co = (cg2<<4) + kgrp*4 + r;
    float bias = a.dsb[co];
    #pragma unroll
    for(int nt=0;nt<4;nt++){
      float y = acc[nt][r] + bias;
      int wcol = (wh<<6) + (nt<<4) + arow;
      a.yout[((size_t)(b*CC+co)*HH_ + h)*WW + wcol] = y;
      vs[r] += y; vq[r] += y*y;
    }
  }
  #pragma unroll
  for(int m=1;m<16;m<<=1){
    #pragma unroll
    for(int r=0;r<4;r++){ vs[r]+=__shfl_xor(vs[r],m); vq[r]+=__shfl_xor(vq[r],m); }
  }
  if(arow==0){
    #pragma unroll
    for(int r=0;r<4;r++){
      int co = (cg2<<4)+kgrp*4+r;
      int pi = (b*CC+co)*256 + h*2 + wh;
      a.pstats[pi] = vs[r];
      a.pstats[65536+pi] = vq[r];
    }
  }
}

// ---------- P4: GN finalize (blocks 0-63) ----------
__device__ __forceinline__ void phase4(const MegaArgs& a, int wg, int t, char* smem){
  if(wg < 64){
    int lane = t&63, wid = t>>6;
    int b4 = wg>>4, g4 = wg&15;
    float s=0.f, q=0.f;
    if(t<256){
      #pragma unroll
      for(int c4=0;c4<4;c4++){
        int base = (b4*CC + g4*4+c4)*256;
        s += a.pstats[base + t];
        q += a.pstats[65536 + base + t];
      }
    }
    for(int o=32;o>0;o>>=1){ s+=__shfl_down(s,o); q+=__shfl_down(q,o); }
    float* ls = (float*)smem; float* lq = ls+8;
    if(lane==0){ ls[wid]=s; lq[wid]=q; }
    __syncthreads();
    if(t==0){
      float S=0.f, Q=0.f;
      #pragma unroll
      for(int i=0;i<8;i++){ S+=ls[i]; Q+=lq[i]; }
      float inv = 1.0f/(4.0f*HPW);
      float mu = S*inv; float var = Q*inv - mu*mu;
      a.gstat[wg*2]=mu; a.gstat[wg*2+1]=rsqrtf(var+EPSV);
    }
  }
}

// ---------- P5: GN apply + relu (grid-stride, 256 blocks x 8) ----------
__device__ __forceinline__ void phase5(const MegaArgs& a, int wg, int t){
  float4* p = (float4*)a.yout;
  int base = wg*512 + t;
  #pragma unroll
  for(int i=0;i<8;i++){
    int idx = base + i*131072;
    int bc = idx >> 12;
    int bb2 = bc>>6, c = bc&63;
    int gi = bb2*16 + (c>>2);
    float mu = a.gstat[gi*2], rstd = a.gstat[gi*2+1];
    float sc = rstd*a.gng[c], sh = a.gnb[c]-mu*sc;
    float4 v = p[idx];
    v.x = fmaxf(v.x*sc+sh, 0.f);
    v.y = fmaxf(v.y*sc+sh, 0.f);
    v.z = fmaxf(v.z*sc+sh, 0.f);
    v.w = fmaxf(v.w*sc+sh, 0.f);
    p[idx] = v;
  }
}

// ================= cooperative mega-kernel (256 blocks x 512) =================
__global__ __launch_bounds__(512, 2) void k_mega(MegaArgs a)
{
  cg::grid_group grid = cg::this_grid();
  __shared__ __align__(16) char smem[SMEM_BYTES];
  int t = threadIdx.x;
  int wg = blockIdx.x;
  phase0(a, wg, t, smem);
  grid.sync();
  phase1(a, wg, t);
  grid.sync();
  phase2(a, wg, t, smem);
  __syncthreads();
  phase2(a, wg+256, t, smem);
  grid.sync();
  phase3(a, wg, t, smem);
  __syncthreads();
  phase3(a, wg+256, t, smem);
  grid.sync();
  phase4(a, wg, t, smem);
  grid.sync();
  phase5(a, wg, t);
}

// ================= fallback wrappers (same phases, separate launches) =================
__global__ __launch_bounds__(512) void k_p0(MegaArgs a){
  __shared__ __align__(16) char smem[64]; // only ls[8] needed
  phase0(a, blockIdx.x, threadIdx.x, smem);
}
__global__ __launch_bounds__(64) void k_p1(MegaArgs a){
  phase1(a, blockIdx.x, threadIdx.x);
}
__global__ __launch_bounds__(512) void k_p2(MegaArgs a){
  __shared__ __align__(16) char smem[SMEM_BYTES];
  phase2(a, blockIdx.x, threadIdx.x, smem);
}
__global__ __launch_bounds__(512) void k_p3(MegaArgs a){
  __shared__ __align__(16) char smem[SMEM_BYTES];
  phase3(a, blockIdx.x, threadIdx.x, smem);
}
__global__ __launch_bounds__(512) void k_p4(MegaArgs a){
  __shared__ __align__(16) char smem[64];
  phase4(a, blockIdx.x, threadIdx.x, smem);
}
__global__ __launch_bounds__(512) void k_p5(MegaArgs a){
  phase5(a, blockIdx.x, threadIdx.x);
}

extern "C" void kernel_launch(void* const* d_in, const int* in_sizes, int n_in,
                              void* d_out, int out_size, void* d_ws, size_t ws_size,
                              hipStream_t stream) {
  float* ws = (float*)d_ws;
  MegaArgs a;
  a.x      = (const float*)d_in[0];
  a.weight = (const float*)d_in[1];
  a.ratio  = (const float*)d_in[2];
  a.o1fc   = (const float*)d_in[3];
  a.o1g    = (const float*)d_in[4];
  a.o1b    = (const float*)d_in[5];
  a.o1m    = (const float*)d_in[6];
  a.o1v    = (const float*)d_in[7];
  a.o1cw   = (const float*)d_in[8];
  a.o1cb   = (const float*)d_in[9];
  a.o1fw   = (const float*)d_in[10];
  a.o1fb   = (const float*)d_in[11];
  a.o2fc   = (const float*)d_in[12];
  a.o2g    = (const float*)d_in[13];
  a.o2b    = (const float*)d_in[14];
  a.o2m    = (const float*)d_in[15];
  a.o2v    = (const float*)d_in[16];
  a.o2cw   = (const float*)d_in[17];
  a.o2cb   = (const float*)d_in[18];
  a.o2fw   = (const float*)d_in[19];
  a.o2fb   = (const float*)d_in[20];
  a.spw    = (const float*)d_in[21];
  a.spb    = (const float*)d_in[22];
  a.offw   = (const float*)d_in[23];
  a.offb   = (const float*)d_in[24];
  a.obg    = (const float*)d_in[25];
  a.obb    = (const float*)d_in[26];
  a.obm    = (const float*)d_in[27];
  a.obv    = (const float*)d_in[28];
  a.dsw    = (const float*)d_in[29];
  a.dsb    = (const float*)d_in[30];
  a.gng    = (const float*)d_in[31];
  a.gnb    = (const float*)d_in[32];

  a.HHb    = ws;                               // 1048576
  a.weff   = ws + 1048576;                     // 2304
  a.partial= ws + 1050880;                     // 512
  a.gstat  = ws + 1051392;                     // 128
  a.dsWbf  = (ushort_t*)(ws + 1051520);        // 28672 shorts
  a.offAbf = (ushort_t*)(ws + 1065856);        // 9216 shorts
  a.pstats = ws + 1070464;                     // 131072
  a.outT   = ws + 1201536;                     // 4194304
  a.outTbf = (ushort_t*)(ws + 5395840);        // 4*128*130*64 shorts
  a.yout   = (float*)d_out;

  void* kargs[] = { (void*)&a };
  hipError_t err = hipLaunchCooperativeKernel((const void*)k_mega, dim3(256), dim3(512),
                                              kargs, 0, stream);
  if(err != hipSuccess){
    // deterministic fallback: same phases as separate launches
    k_p0<<<256,512,0,stream>>>(a);
    k_p1<<<256, 64,0,stream>>>(a);
    k_p2<<<512,512,0,stream>>>(a);
    k_p3<<<512,512,0,stream>>>(a);
    k_p4<<< 64,512,0,stream>>>(a);
    k_p5<<<256,512,0,stream>>>(a);
  }
}

// Round 10
// 95.874 us; speedup vs baseline: 2.9142x; 2.9142x over previous
//
#include <hip/hip_runtime.h>
#include <math.h>

#define BB 4
#define CC 64
#define HH_ 128
#define WW 128
#define HPW (HH_*WW)     // 16384
#define KH 64
#define KW 64
#define KSZ 7
#define AA 16
#define EPSV 1e-5f
#define KTOT 448         // 7*64

typedef __attribute__((ext_vector_type(8))) short bf16x8;
typedef __attribute__((ext_vector_type(4))) float f32x4;
typedef unsigned short ushort_t;

__device__ __forceinline__ float sigm(float x){ return 1.0f/(1.0f+expf(-x)); }
__device__ __forceinline__ unsigned short f2bf(float f){
  unsigned u = __float_as_uint(f);
  return (unsigned short)((u + 0x7fffu + ((u>>16)&1u)) >> 16);
}

// ---------------- K1: prep + DWT-HH + mean partials (512 x 512) ----------------
__global__ __launch_bounds__(512) void k_dwt0(const float* __restrict__ x,
  const float* __restrict__ dsw, const float* __restrict__ offw,
  float* __restrict__ HHb, float* __restrict__ partial,
  ushort_t* __restrict__ dsWbf, ushort_t* __restrict__ offAbf)
{
  int t = threadIdx.x; int wg = blockIdx.x;
  int idx = wg*512 + t;
  if(idx < CC*KTOT){
    int co = idx/KTOT; int K = idx%KTOT; int k = K>>6; int ci = K&63;
    dsWbf[idx] = f2bf(dsw[(size_t)(co*CC+ci)*KSZ + k]);
  } else {
    int j2 = idx - CC*KTOT;
    if(j2 < 18*16*32){
      int kl = j2&31; int co = (j2>>5)&15; int s = j2>>9;
      int tap = s>>1; int ci = (s&1)*32 + kl;
      float v = 0.f;
      if(co<KSZ) v = offw[((size_t)co*CC + ci)*9 + tap];
      offAbf[j2] = f2bf(v);
    }
  }
  int lane = t&63, wid = t>>6;
  int e0 = wg*2048 + t*4;
  int bc = e0>>12; int h2 = (e0>>6)&63; int w0 = e0&63;
  const float* xp = x + (size_t)bc*HPW;
  float4 a0 = *(const float4*)(xp + (2*h2)*WW + 2*w0);
  float4 a1 = *(const float4*)(xp + (2*h2)*WW + 2*w0 + 4);
  float4 b0 = *(const float4*)(xp + (2*h2+1)*WW + 2*w0);
  float4 b1 = *(const float4*)(xp + (2*h2+1)*WW + 2*w0 + 4);
  float4 hh;
  hh.x = 0.5f*(a0.x - b0.x - a0.y + b0.y);
  hh.y = 0.5f*(a0.z - b0.z - a0.w + b0.w);
  hh.z = 0.5f*(a1.x - b1.x - a1.y + b1.y);
  hh.w = 0.5f*(a1.z - b1.z - a1.w + b1.w);
  *(float4*)(HHb + e0) = hh;
  float s = a0.x+a0.y+a0.z+a0.w + a1.x+a1.y+a1.z+a1.w
          + b0.x+b0.y+b0.z+b0.w + b1.x+b1.y+b1.z+b1.w;
  for(int o=32;o>0;o>>=1) s += __shfl_down(s,o);
  __shared__ float ls[8];
  if(lane==0) ls[wid] = s;
  __syncthreads();
  if(t==0){
    float tot=0.f;
    #pragma unroll
    for(int k2=0;k2<8;k2++) tot += ls[k2];
    partial[wg] = tot;
  }
}

// ---------------- K2: attention + weff, grid (b,o), 64 thr ----------------
__global__ __launch_bounds__(64) void k_weff2(const float* __restrict__ partial,
  const float* __restrict__ w, const float* __restrict__ ratio_p,
  const float* __restrict__ o1fc, const float* __restrict__ o1g,const float* __restrict__ o1b,
  const float* __restrict__ o1m,const float* __restrict__ o1v,
  const float* __restrict__ o1cw,const float* __restrict__ o1cb,
  const float* __restrict__ o1fw,const float* __restrict__ o1fb,
  const float* __restrict__ o2fc, const float* __restrict__ o2g,const float* __restrict__ o2b,
  const float* __restrict__ o2m,const float* __restrict__ o2v,
  const float* __restrict__ o2cw,const float* __restrict__ o2cb,
  const float* __restrict__ o2fw,const float* __restrict__ o2fb,
  const float* __restrict__ spw,const float* __restrict__ spb,
  float* __restrict__ weff)
{
  int bo = blockIdx.x; int b = bo>>6, o = bo&63; int ci = threadIdx.x;
  int bc = b*CC+ci;
  float g_own = (partial[2*bc] + partial[2*bc+1]) * (1.0f/HPW);
  float d1=o1cb[ci], d2=o1fb[ci], d3=o2cb[ci], d4=o2fb[ci];
  float sspacc[9];
  #pragma unroll
  for(int e=0;e<9;e++) sspacc[e]=spb[e];
  for(int j=0;j<AA;j++){
    float p1 = g_own * o1fc[j*CC+ci];
    float p2 = g_own * o2fc[j*CC+ci];
    #pragma unroll
    for(int off=32;off>0;off>>=1){ p1+=__shfl_xor(p1,off); p2+=__shfl_xor(p2,off); }
    p1 = (p1-o1m[j])*rsqrtf(o1v[j]+EPSV)*o1g[j]+o1b[j]; p1=fmaxf(p1,0.f);
    p2 = (p2-o2m[j])*rsqrtf(o2v[j]+EPSV)*o2g[j]+o2b[j]; p2=fmaxf(p2,0.f);
    d1 += p1*o1cw[ci*AA+j]; d2 += p1*o1fw[ci*AA+j];
    d3 += p2*o2cw[ci*AA+j]; d4 += p2*o2fw[ci*AA+j];
    #pragma unroll
    for(int e=0;e<9;e++) sspacc[e] += p2*spw[e*AA+j];
  }
  float sc1v=sigm(d1), sc2v=sigm(d3);
  float sf1o=__shfl(sigm(d2),o), sf2o=__shfl(sigm(d4),o);
  const float* wp = w + (size_t)(o*CC+ci)*9;
  float w9[9]; float m=0.f;
  #pragma unroll
  for(int e=0;e<9;e++){ w9[e]=wp[e]; m+=w9[e]; }
  m *= (1.0f/9.0f);
  float S1 = m * sc1v;
  float M[9];
  #pragma unroll
  for(int e=0;e<9;e++) M[e] = (w9[e]-m)*sc2v;
  #pragma unroll
  for(int off=32; off>0; off>>=1){
    S1 += __shfl_xor(S1, off);
    #pragma unroll
    for(int e=0;e<9;e++) M[e] += __shfl_xor(M[e], off);
  }
  if(ci==0){
    const float Dm[3][3] = {{2.f,2.f,2.f},{1.7320508075688772f,0.f,-1.7320508075688772f},{1.f,-2.f,1.f}};
    const float Di[3][3] = {{0.16666666666666666f,0.28867513459481287f,0.16666666666666666f},
                            {0.16666666666666666f,0.f,-0.3333333333333333f},
                            {0.16666666666666666f,-0.28867513459481287f,0.16666666666666666f}};
    float U[3][3], T[3][3], V[3][3], R[3][3];
    for(int k=0;k<3;k++)for(int n=0;n<3;n++) U[k][n]=Dm[k][0]*M[0*3+n]+Dm[k][1]*M[1*3+n]+Dm[k][2]*M[2*3+n];
    for(int k=0;k<3;k++)for(int l=0;l<3;l++) T[k][l]=(U[k][0]*Dm[l][0]+U[k][1]*Dm[l][1]+U[k][2]*Dm[l][2])*2.0f*sigm(sspacc[k*3+l]);
    for(int k=0;k<3;k++)for(int n=0;n<3;n++) V[k][n]=Di[k][0]*T[0][n]+Di[k][1]*T[1][n]+Di[k][2]*T[2][n];
    for(int k=0;k<3;k++)for(int l=0;l<3;l++) R[k][l]=V[k][0]*Di[l][0]+V[k][1]*Di[l][1]+V[k][2]*Di[l][2];
    float rr = ratio_p[0];
    float base = rr*4.0f*sf1o*S1;
    float w2f = (1.0f-rr)*4.0f*sf2o;
    #pragma unroll
    for(int e=0;e<9;e++) weff[(size_t)bo*9+e] = base + w2f*R[e/3][e%3];
  }
}

// ---------------- K3: iwt + transpose, LDS-staged HH conv ----------------
// LDS: hs[32][3][66] (25.3KB, aliased with xt[64][129] 33KB) + d_s[64][65] (16.6KB)
__global__ __launch_bounds__(256) void k_iwtT(const float* __restrict__ HHb,
  const float* __restrict__ x, const float* __restrict__ weff,
  float* __restrict__ outT, ushort_t* __restrict__ outTbf)
{
  __shared__ __align__(16) char smem[33024 + 16640];
  float* hs  = (float*)smem;             // [32][3][66]
  float* xt  = (float*)smem;             // [64][129] (reused after conv)
  float* d_s = (float*)(smem + 33024);   // [64][65]
  int wg = blockIdx.x; int b = wg>>7, h = wg&127; int h2 = h>>1;
  int t = threadIdx.x;
  #pragma unroll
  for(int half=0; half<2; ++half){
    // stage HH rows h2-1..h2+1 for 32 channels, halo-zeroed (66 wide)
    for(int e=t; e<32*3*66; e+=256){
      int c_l = e/198; int rem = e - c_l*198; int r3 = rem/66; int wz = rem - r3*66;
      int r = h2 - 1 + r3; int w2 = wz - 1;
      int c = half*32 + c_l;
      float v = 0.f;
      if(r>=0 && r<KH && w2>=0 && w2<KW)
        v = HHb[((size_t)(b*CC+c))*(KH*KW) + r*KW + w2];
      hs[(c_l*3 + r3)*66 + wz] = v;
    }
    __syncthreads();
    // conv: 256 thr = (c_l 0..31, q 0..7), 8 w2 each
    {
      int c_l = t>>3, q = t&7;
      int c = half*32 + c_l;
      float wk[9];
      #pragma unroll
      for(int e=0;e<9;e++) wk[e] = weff[(size_t)(b*CC+c)*9+e];
      const float* hb = hs + c_l*198;
      #pragma unroll
      for(int j=0;j<8;j++){
        int w2 = q*8+j;
        float conv = 0.f;
        #pragma unroll
        for(int dh=0;dh<3;dh++){
          const float* hr = hb + dh*66 + w2;
          conv += wk[dh*3+0]*hr[0] + wk[dh*3+1]*hr[1] + wk[dh*3+2]*hr[2];
        }
        d_s[c*65+w2] = 0.5f*(conv - hb[1*66 + w2 + 1]);
      }
    }
    __syncthreads();
  }
  // stage x row h (overwrites hs region)
  for(int e=t; e<CC*WW; e+=256){
    int cc=e>>7, w=e&127;
    xt[cc*129+w] = x[((size_t)(b*CC+cc)*HH_+h)*WW + w];
  }
  __syncthreads();
  float* dst = outT + ((size_t)(b*HH_+h))*WW*CC;
  ushort_t* dstb = outTbf + ((size_t)(b*HH_+h))*130*CC;
  for(int e=t; e<CC*WW; e+=256){
    int w=e>>6, cc=e&63;
    float dv = d_s[cc*65+(w>>1)];
    float val = 2.f*xt[cc*129+w] + (((h + w)&1) ? -dv : dv);
    dst[e] = val;
    dstb[(w+1)*CC + cc] = f2bf(val);
  }
  if(t<128){ int cc=t&63; int side=t>>6; dstb[(size_t)side*129*CC + cc] = 0; }
}

// ---------------- K4: fused offset-conv + dy + deform-sample GEMM + GN partials ----------------
__global__ __launch_bounds__(512) void k_dsfused(const float* __restrict__ outT,
  const ushort_t* __restrict__ outTbf, const ushort_t* __restrict__ dsWbf,
  const ushort_t* __restrict__ offAbf, const float* __restrict__ offb,
  const float* __restrict__ obg, const float* __restrict__ obb,
  const float* __restrict__ obm, const float* __restrict__ obv,
  const float* __restrict__ dsb, float* __restrict__ yout, float* __restrict__ pstats)
{
  __shared__ ushort_t S2a[2*8192];
  __shared__ int sb0[KSZ*128], sb1[KSZ*128];
  __shared__ float swr[KSZ*128];
  __shared__ float off_s[KSZ*128];
  __shared__ float dy_s[KSZ*128];
  int t = threadIdx.x;
  int wg = blockIdx.x; int sw = (wg&7)*64 + (wg>>3);   // XCD swizzle
  int b = sw>>7, h = sw&127;
  int lane = t&63, wid = t>>6;
  int arow = lane&15, kgrp = lane>>4;
  // Phase A: offset conv (8 waves, wave = one 16-wide w tile)
  {
    f32x4 acc = (f32x4){0.f,0.f,0.f,0.f};
    #pragma unroll
    for(int s=0;s<18;s++){
      int tap = s>>1, chalf = s&1;
      int r = tap/3, dwp = tap%3;
      int hr = h - 1 + r;
      if(hr<0 || hr>=HH_) continue;
      bf16x8 aF = *(const bf16x8*)(offAbf + (s*16+arow)*32 + kgrp*8);
      const ushort_t* base = outTbf + ((size_t)(b*HH_+hr))*130*CC + chalf*32 + kgrp*8;
      int wp = (wid<<4) + arow + dwp;
      bf16x8 bF = *(const bf16x8*)(base + (size_t)wp*CC);
      acc = __builtin_amdgcn_mfma_f32_16x16x32_bf16(aF, bF, acc, 0,0,0);
    }
    #pragma unroll
    for(int r=0;r<4;r++){
      int co = kgrp*4+r;
      if(co<KSZ) off_s[co*128 + (wid<<4) + arow] = acc[r];
    }
  }
  __syncthreads();
  // Phase B: BN + tanh + cumsum
  if(t<128){
    int w = t;
    float y[KSZ];
    #pragma unroll
    for(int k=0;k<KSZ;k++){
      float sc = obg[k]*rsqrtf(obv[k]+EPSV);
      float sh = obb[k]-obm[k]*sc;
      y[k] = tanhf((off_s[k*128+w]+offb[k])*sc+sh);
    }
    dy_s[      w]=y[0]+y[1]+y[2]; dy_s[128+w]=y[1]+y[2]; dy_s[256+w]=y[2];
    dy_s[384+w]=0.f; dy_s[512+w]=y[4]; dy_s[640+w]=y[4]+y[5]; dy_s[768+w]=y[4]+y[5]+y[6];
  }
  __syncthreads();
  // Phase C: sample meta
  for(int e=t; e<KSZ*128; e+=512){
    int k = e>>7, w = e&127;
    float dv = dy_s[e];
    float r = fminf(fmaxf((float)h + dv, 0.f), 127.f);
    float rf = floorf(r); int r0=(int)rf; float wr=r-rf; int r1=min(r0+1,127);
    int c = min(max(w+k-3,0),127);
    sb0[k*128+w] = ((b*HH_+r0)*WW+c)*CC;
    sb1[k*128+w] = ((b*HH_+r1)*WW+c)*CC;
    swr[k*128+w] = wr;
  }
  __syncthreads();
  // Phase D: K-chunked double-buffered sample + MFMA GEMM
  int cg2 = wid&3, wh = wid>>2;
  {
    ushort_t* buf = S2a;
    #pragma unroll
    for(int i=0;i<16;i++){
      int p = (wid<<4)+i;
      int b0=sb0[p], b1=sb1[p]; float wr=swr[p];
      float av = outT[b0+lane], c2 = outT[b1+lane];
      float v = av + wr*(c2-av);
      int idx = (p<<6)|lane;
      buf[idx ^ ((p&7)<<3)] = f2bf(v);
    }
  }
  __syncthreads();
  f32x4 acc[4];
  #pragma unroll
  for(int nt=0;nt<4;nt++) acc[nt] = (f32x4){0.f,0.f,0.f,0.f};
  int bufs = 0;
  for(int k=0;k<KSZ;k++){
    const ushort_t* Wp = dsWbf + (size_t)((cg2<<4)+arow)*KTOT + (k<<6) + kgrp*8;
    bf16x8 a0 = *(const bf16x8*)Wp;
    bf16x8 a1 = *(const bf16x8*)(Wp+32);
    if(k+1<KSZ){
      ushort_t* nb = S2a + (bufs^1)*8192;
      #pragma unroll
      for(int i=0;i<16;i++){
        int p = (wid<<4)+i;
        int b0=sb0[(k+1)*128+p], b1=sb1[(k+1)*128+p]; float wr=swr[(k+1)*128+p];
        float av = outT[b0+lane], c2 = outT[b1+lane];
        float v = av + wr*(c2-av);
        int idx = (p<<6)|lane;
        nb[idx ^ ((p&7)<<3)] = f2bf(v);
      }
    }
    const ushort_t* cb = S2a + bufs*8192;
    #pragma unroll
    for(int nt=0;nt<4;nt++){
      int pos = (wh<<6) + (nt<<4) + arow;
      int i0 = (pos<<6) + kgrp*8;
      int sz = (pos&7)<<3;
      bf16x8 b0 = *(const bf16x8*)(cb + (i0 ^ sz));
      bf16x8 b1 = *(const bf16x8*)(cb + ((i0+32) ^ sz));
      acc[nt] = __builtin_amdgcn_mfma_f32_16x16x32_bf16(a0, b0, acc[nt], 0,0,0);
      acc[nt] = __builtin_amdgcn_mfma_f32_16x16x32_bf16(a1, b1, acc[nt], 0,0,0);
    }
    __syncthreads();
    bufs ^= 1;
  }
  // epilogue: y + GN partials
  float vs[4]={0.f,0.f,0.f,0.f}, vq[4]={0.f,0.f,0.f,0.f};
  #pragma unroll
  for(int r=0;r<4;r++){
    int co = (cg2<<4) + kgrp*4 + r;
    float bias = dsb[co];
    #pragma unroll
    for(int nt=0;nt<4;nt++){
      float y = acc[nt][r] + bias;
      int wcol = (wh<<6) + (nt<<4) + arow;
      yout[((size_t)(b*CC+co)*HH_ + h)*WW + wcol] = y;
      vs[r] += y; vq[r] += y*y;
    }
  }
  #pragma unroll
  for(int m=1;m<16;m<<=1){
    #pragma unroll
    for(int r=0;r<4;r++){ vs[r]+=__shfl_xor(vs[r],m); vq[r]+=__shfl_xor(vq[r],m); }
  }
  if(arow==0){
    #pragma unroll
    for(int r=0;r<4;r++){
      int co = (cg2<<4)+kgrp*4+r;
      int pi = (b*CC+co)*256 + h*2 + wh;
      pstats[pi] = vs[r];
      pstats[65536+pi] = vq[r];
    }
  }
}

// ---------------- K5: reduce GN partials -> group stats ----------------
__global__ __launch_bounds__(256) void k_gnfin2(const float* __restrict__ pstats,
                                                float* __restrict__ gstat){
  int bg = blockIdx.x; int b = bg>>4, g = bg&15; int t = threadIdx.x;
  float s=0.f, q=0.f;
  #pragma unroll
  for(int c4=0;c4<4;c4++){
    int base = (b*CC + g*4+c4)*256;
    s += pstats[base + t];
    q += pstats[65536 + base + t];
  }
  for(int o=32;o>0;o>>=1){ s+=__shfl_down(s,o); q+=__shfl_down(q,o); }
  __shared__ float ls[4], lq[4];
  if((t&63)==0){ ls[t>>6]=s; lq[t>>6]=q; }
  __syncthreads();
  if(t==0){
    float S=ls[0]+ls[1]+ls[2]+ls[3], Q=lq[0]+lq[1]+lq[2]+lq[3];
    float inv = 1.0f/(4.0f*HPW);
    float mu = S*inv; float var = Q*inv - mu*mu;
    gstat[bg*2]=mu; gstat[bg*2+1]=rsqrtf(var+EPSV);
  }
}

// ---------------- K6: apply GN + affine + relu in place ----------------
__global__ void k_gnapply(float* __restrict__ y, const float* __restrict__ gstat,
  const float* __restrict__ gg, const float* __restrict__ gb){
  int idx = blockIdx.x*256 + threadIdx.x;
  float4* p = (float4*)y;
  int bc = idx >> 12;
  int b = bc>>6, c = bc&63;
  int gi = b*16 + (c>>2);
  float mu = gstat[gi*2], rstd = gstat[gi*2+1];
  float sc = rstd*gg[c], sh = gb[c]-mu*sc;
  float4 v = p[idx];
  v.x = fmaxf(v.x*sc+sh, 0.f);
  v.y = fmaxf(v.y*sc+sh, 0.f);
  v.z = fmaxf(v.z*sc+sh, 0.f);
  v.w = fmaxf(v.w*sc+sh, 0.f);
  p[idx] = v;
}

extern "C" void kernel_launch(void* const* d_in, const int* in_sizes, int n_in,
                              void* d_out, int out_size, void* d_ws, size_t ws_size,
                              hipStream_t stream) {
  const float* x      = (const float*)d_in[0];
  const float* weight = (const float*)d_in[1];
  const float* ratio  = (const float*)d_in[2];
  const float* o1fc   = (const float*)d_in[3];
  const float* o1g    = (const float*)d_in[4];
  const float* o1b    = (const float*)d_in[5];
  const float* o1m    = (const float*)d_in[6];
  const float* o1v    = (const float*)d_in[7];
  const float* o1cw   = (const float*)d_in[8];
  const float* o1cb   = (const float*)d_in[9];
  const float* o1fw   = (const float*)d_in[10];
  const float* o1fb   = (const float*)d_in[11];
  const float* o2fc   = (const float*)d_in[12];
  const float* o2g    = (const float*)d_in[13];
  const float* o2b    = (const float*)d_in[14];
  const float* o2m    = (const float*)d_in[15];
  const float* o2v    = (const float*)d_in[16];
  const float* o2cw   = (const float*)d_in[17];
  const float* o2cb   = (const float*)d_in[18];
  const float* o2fw   = (const float*)d_in[19];
  const float* o2fb   = (const float*)d_in[20];
  const float* spw    = (const float*)d_in[21];
  const float* spb    = (const float*)d_in[22];
  const float* offw   = (const float*)d_in[23];
  const float* offb   = (const float*)d_in[24];
  const float* obg    = (const float*)d_in[25];
  const float* obb    = (const float*)d_in[26];
  const float* obm    = (const float*)d_in[27];
  const float* obv    = (const float*)d_in[28];
  const float* dsw    = (const float*)d_in[29];
  const float* dsb    = (const float*)d_in[30];
  const float* gng    = (const float*)d_in[31];
  const float* gnb    = (const float*)d_in[32];

  float* ws    = (float*)d_ws;
  float* HHb   = ws;                            // 1048576
  float* partial = ws + 1048576;                // 512
  float* weff  = ws + 1049088;                  // 2304
  float* gstat = ws + 1051392;                  // 128
  ushort_t* dsWbf  = (ushort_t*)(ws + 1051520); // 28672 shorts
  ushort_t* offAbf = (ushort_t*)(ws + 1065856); // 9216 shorts
  float* pstats= ws + 1070464;                  // 131072
  float* outT  = ws + 1201536;                  // 4194304
  ushort_t* outTbf = (ushort_t*)(ws + 5395840); // 4*128*130*64 shorts
  float* outb  = (float*)d_out;

  k_dwt0<<<512,512,0,stream>>>(x, dsw, offw, HHb, partial, dsWbf, offAbf);
  k_weff2<<<256,64,0,stream>>>(partial, weight, ratio,
    o1fc,o1g,o1b,o1m,o1v,o1cw,o1cb,o1fw,o1fb,
    o2fc,o2g,o2b,o2m,o2v,o2cw,o2cb,o2fw,o2fb,
    spw,spb, weff);
  k_iwtT<<<512,256,0,stream>>>(HHb, x, weff, outT, outTbf);
  k_dsfused<<<512,512,0,stream>>>(outT, outTbf, dsWbf, offAbf,
    offb, obg, obb, obm, obv, dsb, outb, pstats);
  k_gnfin2<<<64,256,0,stream>>>(pstats, gstat);
  k_gnapply<<<4096,256,0,stream>>>(outb, gstat, gng, gnb);
}